// Round 2
// baseline (182.383 us; speedup 1.0000x reference)
//
#include <hip/hip_runtime.h>
#include <hip/hip_bf16.h>
#include <stdint.h>

#define B_      4
#define CIN     512
#define COUT    512
#define L_      4096
#define K_      7
#define OUT_LEN 4090

typedef unsigned short ushort_t;
typedef __attribute__((ext_vector_type(8))) __bf16 bf16x8;
typedef __attribute__((ext_vector_type(4))) float f32x4;

__device__ __forceinline__ uint32_t f2bf(float f) {
    uint32_t u = __float_as_uint(f);
    return (u + 0x7fffu + ((u >> 16) & 1u)) >> 16;
}

__device__ __forceinline__ uint32_t pack2bf(float s0, float s1) {   // s0 -> low 16
    __hip_bfloat162 h = __float22bfloat162_rn(make_float2(s0, s1));
    uint32_t r;
    __builtin_memcpy(&r, &h, 4);
    return r;
}

__device__ __forceinline__ uint32_t interp1(uint32_t wl, uint32_t wh, float g0, float g1) {
    const float l0 = __uint_as_float(wl << 16);
    const float l1 = __uint_as_float(wl & 0xffff0000u);
    const float h0 = __uint_as_float(wh << 16);
    const float h1 = __uint_as_float(wh & 0xffff0000u);
    return pack2bf(g0 * l0 + g1 * h0, g0 * l1 + g1 * h1);
}

__device__ __forceinline__ void async16(const void* g, void* l) {
    __builtin_amdgcn_global_load_lds(
        (const __attribute__((address_space(1))) unsigned int*)g,
        (__attribute__((address_space(3))) unsigned int*)l, 16, 0, 0);
}

// =====================================================================================
//  NEW PATH
//  Layouts (step s = cc*7 + k, s = 0..111):
//   Wr: slab s -> 512 d-rows x 32 bf16 (channels cc*32..+31), 64 B/row,
//       16B-chunk c stored at physical chunk c ^ ((d>>1)&3)      [pre-swizzled]
//   P : slab (s, b, obx) -> 128 o-rows x 32 bf16, 64 B/row,
//       chunk c stored at physical chunk c ^ ((o_loc>>1)&3)      [pre-swizzled]
//  The swizzle makes a wave's 4-frag read (16 rows x 4 chunks) cover a CONTIGUOUS,
//  fully-coalesced 1 KB block, and (row>>1)&3 == (m16>>1)&3 is a per-lane constant.
//  gemm_kernel therefore loads fragments DIRECTLY global->VGPR (no LDS, no barriers).
// =====================================================================================

// ------- weight reorder+cast, step-linear + chunk-swizzled -------
__global__ __launch_bounds__(256)
void reorder_w2_kernel(const float* __restrict__ w, uint32_t* __restrict__ Wr) {
    const int d   = blockIdx.x;
    const int tid = threadIdx.x;
    __shared__ float wrow[3584];
    const float4* src = (const float4*)(w + (size_t)d * 3584);
    for (int e = tid; e < 896; e += 256) ((float4*)wrow)[e] = src[e];
    __syncthreads();
    const int cc  = tid >> 4;
    const int clp = tid & 15;                                   // pair index in chunk (ch 2clp,2clp+1)
    const int pos = (((clp >> 2) ^ ((d >> 1) & 3)) << 2) | (clp & 3);
    #pragma unroll
    for (int k = 0; k < K_; ++k) {
        const float w0 = wrow[tid * 14 + k];
        const float w1 = wrow[tid * 14 + 7 + k];
        Wr[((size_t)(cc * 7 + k) * 512 + d) * 16 + pos] = (f2bf(w1) << 16) | f2bf(w0);
    }
}

// ------- interp+pack: stage x slab -> LDS, interpolate ONCE, write MFMA-ready P -------
__global__ __launch_bounds__(256)
void interp_pack_kernel(const float* __restrict__ x, const float* __restrict__ offs,
                        uint32_t* __restrict__ P) {
    const int obx = blockIdx.x;   // 0..31
    const int cc  = blockIdx.y;   // 0..15
    const int b   = blockIdx.z;
    const int tid = threadIdx.x;
    const int o0  = obx * 128;
    __shared__ __align__(16) uint32_t XT[2176];   // 136 cols x 16 pair-slots (XOR-swizzled)

    // ---- phase 1: x -> XT (bf16 channel-pairs, per-column XOR on pair-group) ----
    const float* xc = x + ((size_t)b * CIN + cc * 32) * L_ + o0;
    #pragma unroll
    for (int r = 0; r < 3; ++r) {
        const int e = r * 256 + tid;
        if (e < 544) {
            const int cp   = e / 34;
            const int col4 = e - cp * 34;
            const int colb = col4 * 4;
            const float* p0 = xc + (size_t)(2 * cp) * L_ + colb;
            const float* p1 = p0 + L_;
            float4 v0, v1;
            if (o0 + colb + 3 < L_) {
                v0 = *(const float4*)p0;
                v1 = *(const float4*)p1;
            } else {
                float a0 = (o0 + colb + 0 < L_) ? p0[0] : 0.f;
                float a1 = (o0 + colb + 1 < L_) ? p0[1] : 0.f;
                float a2 = (o0 + colb + 2 < L_) ? p0[2] : 0.f;
                float a3 = (o0 + colb + 3 < L_) ? p0[3] : 0.f;
                float b0 = (o0 + colb + 0 < L_) ? p1[0] : 0.f;
                float b1 = (o0 + colb + 1 < L_) ? p1[1] : 0.f;
                float b2 = (o0 + colb + 2 < L_) ? p1[2] : 0.f;
                float b3 = (o0 + colb + 3 < L_) ? p1[3] : 0.f;
                v0 = make_float4(a0, a1, a2, a3);
                v1 = make_float4(b0, b1, b2, b3);
            }
            const float* f0 = (const float*)&v0;
            const float* f1 = (const float*)&v1;
            const int cpg = cp >> 1, hh = cp & 1;
            #pragma unroll
            for (int ii = 0; ii < 4; ++ii) {
                const int col = colb + ii;
                XT[col * 16 + (((cpg ^ (col & 7)) << 1) | hh)] = pack2bf(f0[ii], f1[ii]);
            }
        }
    }
    __syncthreads();

    // ---- phase 2: interpolate, write P slabs (chunk-swizzled for coalesced reads) ----
    const int o_loc = tid >> 1;
    const int h     = tid & 1;                    // channel half: pairs 8h..8h+7
    int o = o0 + o_loc; if (o > OUT_LEN - 1) o = OUT_LEN - 1;
    const float t0f = (float)o;
    const int sr = (o_loc >> 1) & 3;
    uint32_t* Pb = P + ((size_t)((b * 16 + cc) * 7) * 32 + obx) * 2048 + o_loc * 16;
    const int c0 = ((2 * h) ^ sr) << 2;
    const int c1 = ((2 * h + 1) ^ sr) << 2;
    #pragma unroll
    for (int k = 0; k < K_; ++k) {
        const float off = offs[((size_t)b * OUT_LEN + o) * K_ + k];
        float T = t0f + (float)k + off;
        T = fmaxf(T, t0f);
        T = fminf(T, t0f + 6.0f);
        int u0 = (int)floorf(T); if (u0 > L_ - 2) u0 = L_ - 2;
        const float g1 = T - (float)u0;           // == max(0,1-|u0+1-T|)
        const float g0 = 1.0f - g1;               // == max(0,1-|u0-T|)
        const int ul = u0 - o0;
        const uint32_t* R0 = &XT[ul * 16];
        const uint32_t* R1 = &XT[(ul + 1) * 16];
        const int s0 = ul & 7, s1 = (ul + 1) & 7;
        uint32_t ow[8];
        #pragma unroll
        for (int q = 0; q < 4; ++q) {
            const int pg = h * 4 + q;             // pair-group -> pairs 2pg,2pg+1
            const uint2 lo = *(const uint2*)&R0[(pg ^ s0) << 1];
            const uint2 hi = *(const uint2*)&R1[(pg ^ s1) << 1];
            ow[q * 2 + 0] = interp1(lo.x, hi.x, g0, g1);
            ow[q * 2 + 1] = interp1(lo.y, hi.y, g0, g1);
        }
        uint32_t* Pk = Pb + (size_t)k * 65536;    // next k-slab: 32 slabs * 2048 u32
        *(uint4*)&Pk[c0] = make_uint4(ow[0], ow[1], ow[2], ow[3]);
        *(uint4*)&Pk[c1] = make_uint4(ow[4], ow[5], ow[6], ow[7]);
    }
}

// ------- zero-LDS, zero-barrier register-pipelined bf16 GEMM (direct L1/L2-fed) -------
__global__ __launch_bounds__(256, 2)
void gemm_kernel(const ushort_t* __restrict__ Wr, const uint32_t* __restrict__ P,
                 const float* __restrict__ bias, float* __restrict__ out) {
    const int bxi  = blockIdx.x;
    const int o0   = bxi * 128;
    const int d0   = blockIdx.y * 128;
    const int b    = blockIdx.z;
    const int tid  = threadIdx.x;
    const int wv   = tid >> 6;
    const int lane = tid & 63;
    const int m16  = lane & 15;
    const int quad = lane >> 4;
    const int wd   = wv >> 1;                     // d-half of wave
    const int wo   = wv & 1;                      // o-half of wave
    const int sw   = (m16 >> 1) & 3;              // == (row>>1)&3 for every fragment row
    const int chk  = quad ^ sw;                   // physical 16B chunk

    // lane base addresses; frag (i,s): Ab + s*16384 + i*512 (ushort units)
    const ushort_t* Ab = Wr + (size_t)(d0 + wd * 64 + m16) * 32 + chk * 8;
    // frag (j,s): Bb + s*65536 + j*256 (u32 units)
    const uint32_t* Bb = P + ((size_t)(b * 112) * 32 + bxi) * 2048
                           + (wo * 64 + m16) * 16 + chk * 4;

#define LDF(AF, BF, S)                                                        \
    { _Pragma("unroll")                                                       \
      for (int i_ = 0; i_ < 4; ++i_)                                          \
          AF[i_] = *(const bf16x8*)(Ab + (size_t)(S) * 16384 + i_ * 512);     \
      _Pragma("unroll")                                                       \
      for (int j_ = 0; j_ < 4; ++j_)                                          \
          BF[j_] = *(const bf16x8*)(Bb + (size_t)(S) * 65536 + j_ * 256); }

#define MFMA16(AF, BF)                                                        \
    { __builtin_amdgcn_s_setprio(1);                                          \
      _Pragma("unroll")                                                       \
      for (int i_ = 0; i_ < 4; ++i_) {                                        \
          _Pragma("unroll")                                                   \
          for (int j_ = 0; j_ < 4; ++j_)                                      \
              acc[i_][j_] = __builtin_amdgcn_mfma_f32_16x16x32_bf16(          \
                  AF[i_], BF[j_], acc[i_][j_], 0, 0, 0);                      \
      }                                                                       \
      __builtin_amdgcn_s_setprio(0); }

    f32x4 acc[4][4];
    #pragma unroll
    for (int i = 0; i < 4; ++i) {
        #pragma unroll
        for (int j = 0; j < 4; ++j) acc[i][j] = (f32x4){0.f, 0.f, 0.f, 0.f};
    }

    bf16x8 aC[4], bC[4], aN[4], bN[4];
    LDF(aC, bC, 0);
    #pragma unroll 1
    for (int s = 0; s < 110; s += 2) {
        LDF(aN, bN, s + 1);
        MFMA16(aC, bC);
        LDF(aC, bC, s + 2);
        MFMA16(aN, bN);
    }
    LDF(aN, bN, 111);
    MFMA16(aC, bC);
    MFMA16(aN, bN);

    // epilogue (verified C/D layout: col=o (m16), row=quad*4+r on the d dim)
    #pragma unroll
    for (int i = 0; i < 4; ++i) {
        const int dd = d0 + wd * 64 + i * 16 + quad * 4;
        float bv[4];
        #pragma unroll
        for (int r = 0; r < 4; ++r) bv[r] = bias[dd + r];
        #pragma unroll
        for (int j = 0; j < 4; ++j) {
            const int oo = o0 + wo * 64 + j * 16 + m16;
            if (oo < OUT_LEN) {
                float* op = out + (size_t)b * COUT * OUT_LEN + (size_t)dd * OUT_LEN + oo;
                #pragma unroll
                for (int r = 0; r < 4; ++r)
                    op[(size_t)r * OUT_LEN] = acc[i][j][r] + bv[r];
            }
        }
    }
#undef LDF
#undef MFMA16
}

// =====================================================================================
//  OLD PATH (verified @186.9us) — used when ws is too small for P (117 MB)
// =====================================================================================

__global__ __launch_bounds__(256)
void reorder_w1_kernel(const float* __restrict__ w, uint32_t* __restrict__ Wr) {
    const int d   = blockIdx.x;
    const int tid = threadIdx.x;
    __shared__ float wrow[3584];
    const float4* src = (const float4*)(w + (size_t)d * 3584);
    for (int e = tid; e < 896; e += 256) ((float4*)wrow)[e] = src[e];
    __syncthreads();
    const int cc  = tid >> 4;
    const int clp = tid & 15;
    #pragma unroll
    for (int k = 0; k < K_; ++k) {
        const float w0 = wrow[tid * 14 + k];
        const float w1 = wrow[tid * 14 + 7 + k];
        Wr[((size_t)((k * 16 + cc) * 512 + d)) * 16 + clp] = (f2bf(w1) << 16) | f2bf(w0);
    }
}

__global__ __launch_bounds__(256)
void prepack_kernel(const float* __restrict__ x, uint32_t* __restrict__ xpack) {
    const int obx = blockIdx.x;   // 0..31
    const int cc  = blockIdx.y;   // 0..15
    const int b   = blockIdx.z;
    const int tid = threadIdx.x;
    const int o0  = obx * 128;
    __shared__ __align__(16) uint32_t XT[2176];
    const float* xc = x + ((size_t)b * CIN + cc * 32) * L_ + o0;
    #pragma unroll
    for (int r = 0; r < 3; ++r) {
        const int e = r * 256 + tid;
        if (e < 544) {
            const int cp   = e / 34;
            const int col4 = e - cp * 34;
            const int colb = col4 * 4;
            const float* p0 = xc + (size_t)(2 * cp) * L_ + colb;
            const float* p1 = p0 + L_;
            float4 v0, v1;
            if (o0 + colb + 3 < L_) {
                v0 = *(const float4*)p0;
                v1 = *(const float4*)p1;
            } else {
                float a0 = (o0 + colb + 0 < L_) ? p0[0] : 0.f;
                float a1 = (o0 + colb + 1 < L_) ? p0[1] : 0.f;
                float a2 = (o0 + colb + 2 < L_) ? p0[2] : 0.f;
                float a3 = (o0 + colb + 3 < L_) ? p0[3] : 0.f;
                float b0 = (o0 + colb + 0 < L_) ? p1[0] : 0.f;
                float b1 = (o0 + colb + 1 < L_) ? p1[1] : 0.f;
                float b2 = (o0 + colb + 2 < L_) ? p1[2] : 0.f;
                float b3 = (o0 + colb + 3 < L_) ? p1[3] : 0.f;
                v0 = make_float4(a0, a1, a2, a3);
                v1 = make_float4(b0, b1, b2, b3);
            }
            const float* f0 = (const float*)&v0;
            const float* f1 = (const float*)&v1;
            const int cpg = cp >> 1, h = cp & 1;
            #pragma unroll
            for (int ii = 0; ii < 4; ++ii) {
                const int col = colb + ii;
                XT[col * 16 + (((cpg ^ (col & 7)) << 1) | h)] = pack2bf(f0[ii], f1[ii]);
            }
        }
    }
    __syncthreads();
    uint4* dst = (uint4*)xpack + (size_t)((b * 16 + cc) * 32 + obx) * 544;
    const uint4* s4 = (const uint4*)XT;
    #pragma unroll
    for (int r = 0; r < 3; ++r) {
        const int e = r * 256 + tid;
        if (e < 544) dst[e] = s4[e];
    }
}

__global__ __launch_bounds__(256, 2)
void fused_v1_kernel(const float* __restrict__ offs, const ushort_t* __restrict__ Wr,
                     const uint32_t* __restrict__ xpack, const float* __restrict__ bias,
                     float* __restrict__ out) {
    const int bxi  = blockIdx.x;
    const int o0   = bxi * 128;
    const int d0   = blockIdx.y * 128;
    const int b    = blockIdx.z;
    const int tid  = threadIdx.x;
    const int wv   = tid >> 6;
    const int lane = tid & 63;
    const int m16  = lane & 15;
    const int quad = lane >> 4;
    const int ob   = wv * 32;
    const int q2   = quad * 2;

    __shared__ __align__(16) ushort_t As0[4096], As1[4096], As2[4096], As3[4096];
    __shared__ __align__(16) uint32_t XTB0[2304], XTB1[2304];
    __shared__ int    SU[896];
    __shared__ float2 PG[896];

#define ISSUE_A(KK, CC, ASP)                                                      \
    {                                                                             \
        _Pragma("unroll")                                                         \
        for (int r_ = 0; r_ < 2; ++r_) {                                          \
            const int c_ = r_ * 256 + tid;                                        \
            const int row_ = c_ >> 2, pc_ = c_ & 3;                               \
            const ushort_t* g_ = Wr                                               \
                + ((size_t)(((KK) * 16 + (CC)) * 512 + d0 + row_)) * 32 + pc_ * 8;\
            async16(g_, (void*)((ASP) + (r_ * 256 + wv * 64) * 8));               \
        }                                                                         \
    }

#define ISSUE_XTB(CC, XP)                                                         \
    {                                                                             \
        const uint32_t* sp_ = xpack + ((size_t)((b * 16 + (CC)) * 32 + bxi)) * 2176; \
        _Pragma("unroll")                                                         \
        for (int r_ = 0; r_ < 3; ++r_) {                                          \
            const int cb_ = r_ * 256 + wv * 64;                                   \
            if (cb_ < 544) {                                                      \
                const int c_ = r_ * 256 + tid;                                    \
                async16((const void*)(sp_ + (size_t)c_ * 4),                      \
                        (void*)((XP) + (size_t)cb_ * 4));                         \
            }                                                                     \
        }                                                                         \
    }

#define STEP(KK, XP, ASP)                                                         \
    {                                                                             \
        bf16x8 af_[8];                                                            \
        _Pragma("unroll")                                                         \
        for (int i_ = 0; i_ < 8; ++i_)                                            \
            af_[i_] = *(const bf16x8*)&(ASP)[(i_ * 16 + m16) * 32 + quad * 8];    \
        bf16x8 bfr_[2];                                                           \
        _Pragma("unroll")                                                         \
        for (int j_ = 0; j_ < 2; ++j_) {                                          \
            const int row_ = ((KK) << 7) | (ob + j_ * 16 + m16);                  \
            const int u_ = SU[row_];                                              \
            const float2 g_ = PG[row_];                                           \
            const uint32_t* Xr0_ = &(XP)[u_ * 16];                                \
            const uint32_t* Xr1_ = Xr0_ + 16;                                     \
            const int s0_ = u_ & 7, s1_ = (u_ + 1) & 7;                           \
            const uint2 a0_ = *(const uint2*)&Xr0_[((q2     ^ s0_) << 1)];        \
            const uint2 a1_ = *(const uint2*)&Xr0_[(((q2+1) ^ s0_) << 1)];        \
            const uint2 c0_ = *(const uint2*)&Xr1_[((q2     ^ s1_) << 1)];        \
            const uint2 c1_ = *(const uint2*)&Xr1_[(((q2+1) ^ s1_) << 1)];        \
            uint4 rr_;                                                            \
            rr_.x = interp1(a0_.x, c0_.x, g_.x, g_.y);                            \
            rr_.y = interp1(a0_.y, c0_.y, g_.x, g_.y);                            \
            rr_.z = interp1(a1_.x, c1_.x, g_.x, g_.y);                            \
            rr_.w = interp1(a1_.y, c1_.y, g_.x, g_.y);                            \
            __builtin_memcpy(&bfr_[j_], &rr_, 16);                                \
        }                                                                         \
        _Pragma("unroll")                                                         \
        for (int i_ = 0; i_ < 8; ++i_) {                                          \
            _Pragma("unroll")                                                     \
            for (int j_ = 0; j_ < 2; ++j_)                                        \
                acc[i_][j_] = __builtin_amdgcn_mfma_f32_16x16x32_bf16(af_[i_], bfr_[j_], acc[i_][j_], 0, 0, 0); \
        }                                                                         \
    }

#define HALF(CCB, A0_, A1_, A2_, A3_)                                             \
    ISSUE_A(2, (CCB), A2_); ISSUE_A(3, (CCB), A3_); ISSUE_XTB((CCB) + 1, XTB1);   \
    STEP(0, XTB0, A0_); STEP(1, XTB0, A1_); __syncthreads();                      \
    ISSUE_A(4, (CCB), A0_); ISSUE_A(5, (CCB), A1_);                               \
    STEP(2, XTB0, A2_); STEP(3, XTB0, A3_); __syncthreads();                      \
    ISSUE_A(6, (CCB), A2_); ISSUE_A(0, (CCB) + 1, A3_);                           \
    STEP(4, XTB0, A0_); STEP(5, XTB0, A1_); __syncthreads();                      \
    ISSUE_A(1, (CCB) + 1, A0_); ISSUE_A(2, (CCB) + 1, A1_);                       \
    STEP(6, XTB0, A2_); STEP(0, XTB1, A3_); __syncthreads();                      \
    ISSUE_A(3, (CCB) + 1, A2_); ISSUE_A(4, (CCB) + 1, A3_);                       \
    if ((CCB) + 2 < 16) { ISSUE_XTB((CCB) + 2, XTB0); }                           \
    STEP(1, XTB1, A0_); STEP(2, XTB1, A1_); __syncthreads();                      \
    ISSUE_A(5, (CCB) + 1, A0_); ISSUE_A(6, (CCB) + 1, A1_);                       \
    STEP(3, XTB1, A2_); STEP(4, XTB1, A3_); __syncthreads();                      \
    if ((CCB) + 2 < 16) { ISSUE_A(0, (CCB) + 2, A2_); ISSUE_A(1, (CCB) + 2, A3_); } \
    STEP(5, XTB1, A0_); STEP(6, XTB1, A1_); __syncthreads();

    f32x4 acc[8][2];
    #pragma unroll
    for (int i = 0; i < 8; ++i) {
        #pragma unroll
        for (int j = 0; j < 2; ++j) acc[i][j] = (f32x4){0.f, 0.f, 0.f, 0.f};
    }

    ISSUE_XTB(0, XTB0);
    ISSUE_A(0, 0, As0);
    ISSUE_A(1, 0, As1);
    for (int e = tid; e < 896; e += 256) {
        const int k  = e >> 7;
        const int ol = e & 127;
        int o = o0 + ol; if (o > OUT_LEN - 1) o = OUT_LEN - 1;
        const float t0  = (float)o;
        const float off = offs[((size_t)b * OUT_LEN + o) * K_ + k];
        float T = t0 + (float)k + off;
        T = fmaxf(T, t0);
        T = fminf(T, t0 + 6.0f);
        int u0 = (int)floorf(T);
        if (u0 > L_ - 2) u0 = L_ - 2;
        const float g0 = fmaxf(1.0f - fabsf((float)u0 - T), 0.0f);
        const float g1 = fmaxf(1.0f - fabsf((float)(u0 + 1) - T), 0.0f);
        SU[e] = u0 - o0;
        PG[e] = make_float2(g0, g1);
    }
    __syncthreads();

    #pragma unroll 1
    for (int s4 = 0; s4 < 16; s4 += 4) {
        HALF(s4,     As0, As1, As2, As3)
        HALF(s4 + 2, As2, As3, As0, As1)
    }

    #pragma unroll
    for (int i = 0; i < 8; ++i) {
        const int dd = d0 + i * 16 + quad * 4;
        float bv[4];
        #pragma unroll
        for (int r = 0; r < 4; ++r) bv[r] = bias[dd + r];
        #pragma unroll
        for (int j = 0; j < 2; ++j) {
            const int oo = o0 + ob + j * 16 + m16;
            if (oo < OUT_LEN) {
                float* op = out + (size_t)b * COUT * OUT_LEN + (size_t)dd * OUT_LEN + oo;
                #pragma unroll
                for (int r = 0; r < 4; ++r)
                    op[(size_t)r * OUT_LEN] = acc[i][j][r] + bv[r];
            }
        }
    }
#undef ISSUE_A
#undef ISSUE_XTB
#undef STEP
#undef HALF
}

// ---------------- fp32 fallback (round-1 kernel, used only if ws too small) ----------------
#define BM 64
#define BN 64
#define BC 8
#define TT (BC * K_)

__global__ __launch_bounds__(256, 2)
void deform_conv1d_fallback(const float* __restrict__ x, const float* __restrict__ offsets,
                            const float* __restrict__ weight, const float* __restrict__ bias,
                            float* __restrict__ out) {
    const int o0 = blockIdx.x * BN, d0 = blockIdx.y * BM, b = blockIdx.z, tid = threadIdx.x;
    __shared__ int   SU[BN * K_];
    __shared__ float SG0[BN * K_], SG1[BN * K_];
    __shared__ float XT[BC][BN + 8];
    __shared__ float S[BC][K_][BN];
    __shared__ float WT[BM][TT + 1];
    for (int e = tid; e < BN * K_; e += 256) {
        const int ol = e / K_, k = e % K_, o = o0 + ol;
        int u0rel = 0; float g0 = 0.f, g1 = 0.f;
        if (o < OUT_LEN) {
            const float t0 = (float)o;
            const float off = offsets[(size_t)b * OUT_LEN * K_ + (size_t)o * K_ + k];
            float T = fminf(fmaxf(t0 + (float)k + off, t0), t0 + 6.0f);
            int u0 = (int)floorf(T); if (u0 > L_ - 2) u0 = L_ - 2;
            g0 = fmaxf(1.0f - fabsf((float)u0 - T), 0.0f);
            g1 = fmaxf(1.0f - fabsf((float)(u0 + 1) - T), 0.0f);
            u0rel = u0 - o0;
        }
        SU[e] = u0rel; SG0[e] = g0; SG1[e] = g1;
    }
    float acc[4][4];
    #pragma unroll
    for (int i = 0; i < 4; ++i) {
        #pragma unroll
        for (int j = 0; j < 4; ++j) acc[i][j] = 0.f;
    }
    const int ty = tid >> 4, tx = tid & 15;
    const float* xb = x + (size_t)b * CIN * L_;
    for (int c0 = 0; c0 < CIN; c0 += BC) {
        __syncthreads();
        for (int e = tid; e < BC * (BN + 7); e += 256) {
            const int cl = e / (BN + 7), j = e % (BN + 7), pos = o0 + j;
            XT[cl][j] = (pos < L_) ? xb[(size_t)(c0 + cl) * L_ + pos] : 0.f;
        }
        for (int e = tid; e < BM * TT; e += 256) {
            const int d = e / TT, t = e % TT;
            WT[d][t] = weight[(size_t)(d0 + d) * (CIN * K_) + c0 * K_ + t];
        }
        __syncthreads();
        for (int e = tid; e < BC * K_ * BN; e += 256) {
            const int cl = e / (K_ * BN), r = e % (K_ * BN), k = r / BN, ol = r % BN;
            const int p = ol * K_ + k, u = SU[p];
            S[cl][k][ol] = SG0[p] * XT[cl][u] + SG1[p] * XT[cl][u + 1];
        }
        __syncthreads();
        #pragma unroll
        for (int t = 0; t < TT; ++t) {
            const int cl = t / K_, k = t % K_;
            const float4 s4 = *(const float4*)&S[cl][k][tx * 4];
            const float w0 = WT[ty * 4 + 0][t], w1 = WT[ty * 4 + 1][t];
            const float w2 = WT[ty * 4 + 2][t], w3 = WT[ty * 4 + 3][t];
            acc[0][0] += w0 * s4.x; acc[0][1] += w0 * s4.y; acc[0][2] += w0 * s4.z; acc[0][3] += w0 * s4.w;
            acc[1][0] += w1 * s4.x; acc[1][1] += w1 * s4.y; acc[1][2] += w1 * s4.z; acc[1][3] += w1 * s4.w;
            acc[2][0] += w2 * s4.x; acc[2][1] += w2 * s4.y; acc[2][2] += w2 * s4.z; acc[2][3] += w2 * s4.w;
            acc[3][0] += w3 * s4.x; acc[3][1] += w3 * s4.y; acc[3][2] += w3 * s4.z; acc[3][3] += w3 * s4.w;
        }
    }
    #pragma unroll
    for (int i = 0; i < 4; ++i) {
        const int d = d0 + ty * 4 + i;
        const float bvv = bias[d];
        #pragma unroll
        for (int j = 0; j < 4; ++j) {
            const int o = o0 + tx * 4 + j;
            if (o < OUT_LEN)
                out[(size_t)b * COUT * OUT_LEN + (size_t)d * OUT_LEN + o] = acc[i][j] + bvv;
        }
    }
}

extern "C" void kernel_launch(void* const* d_in, const int* in_sizes, int n_in,
                              void* d_out, int out_size, void* d_ws, size_t ws_size,
                              hipStream_t stream) {
    const float* x       = (const float*)d_in[0];
    const float* offsets = (const float*)d_in[1];
    const float* weight  = (const float*)d_in[2];
    const float* bias    = (const float*)d_in[3];
    float* out = (float*)d_out;

    const size_t WR_BYTES = (size_t)512 * 512 * 7 * 2;                  // 3,670,016
    const size_t P_BYTES  = (size_t)4 * 16 * 7 * 32 * 8192;             // 117,440,512
    const size_t XP_BYTES = (size_t)2048 * 544 * 16 + 512;              // 17,826,304

    if (ws_size >= WR_BYTES + P_BYTES) {
        // new path: precomputed interp + zero-LDS register-pipelined GEMM
        uint32_t* Wr_u32 = (uint32_t*)d_ws;
        ushort_t* Wr     = (ushort_t*)d_ws;
        uint32_t* P      = (uint32_t*)((char*)d_ws + WR_BYTES);
        reorder_w2_kernel<<<512, 256, 0, stream>>>(weight, Wr_u32);
        interp_pack_kernel<<<dim3(32, 16, B_), 256, 0, stream>>>(x, offsets, P);
        gemm_kernel<<<dim3(32, 4, B_), 256, 0, stream>>>(Wr, P, bias, out);
        return;
    }

    if (ws_size >= WR_BYTES + XP_BYTES) {
        // old verified path
        uint32_t* Wr_u32 = (uint32_t*)d_ws;
        ushort_t* Wr     = (ushort_t*)d_ws;
        uint32_t* xpack  = (uint32_t*)((char*)d_ws + WR_BYTES);
        reorder_w1_kernel<<<512, 256, 0, stream>>>(weight, Wr_u32);
        prepack_kernel<<<dim3(32, 16, B_), 256, 0, stream>>>(x, xpack);
        fused_v1_kernel<<<dim3(32, 4, B_), 256, 0, stream>>>(offsets, Wr, xpack, bias, out);
        return;
    }

    dim3 grid((OUT_LEN + BN - 1) / BN, COUT / BM, B_);
    deform_conv1d_fallback<<<grid, 256, 0, stream>>>(x, offsets, weight, bias, out);
}

// Round 3
// 179.781 us; speedup vs baseline: 1.0145x; 1.0145x over previous
//
#include <hip/hip_runtime.h>
#include <hip/hip_bf16.h>
#include <stdint.h>

#define B_      4
#define CIN     512
#define COUT    512
#define L_      4096
#define K_      7
#define OUT_LEN 4090

typedef unsigned short ushort_t;
typedef __attribute__((ext_vector_type(8))) __bf16 bf16x8;
typedef __attribute__((ext_vector_type(4))) float f32x4;

__device__ __forceinline__ uint32_t f2bf(float f) {
    uint32_t u = __float_as_uint(f);
    return (u + 0x7fffu + ((u >> 16) & 1u)) >> 16;
}

__device__ __forceinline__ uint32_t pack2bf(float s0, float s1) {   // s0 -> low 16
    __hip_bfloat162 h = __float22bfloat162_rn(make_float2(s0, s1));
    uint32_t r;
    __builtin_memcpy(&r, &h, 4);
    return r;
}

__device__ __forceinline__ uint32_t interp1(uint32_t wl, uint32_t wh, float g0, float g1) {
    const float l0 = __uint_as_float(wl << 16);
    const float l1 = __uint_as_float(wl & 0xffff0000u);
    const float h0 = __uint_as_float(wh << 16);
    const float h1 = __uint_as_float(wh & 0xffff0000u);
    return pack2bf(g0 * l0 + g1 * h0, g0 * l1 + g1 * h1);
}

__device__ __forceinline__ void async16(const void* g, void* l) {
    __builtin_amdgcn_global_load_lds(
        (const __attribute__((address_space(1))) unsigned int*)g,
        (__attribute__((address_space(3))) unsigned int*)l, 16, 0, 0);
}

// =====================================================================================
//  NEW PATH
//  Layouts (step s = cc*7 + k, s = 0..111):
//   Wr: slab s -> 512 d-rows x 32 bf16 (channels cc*32..+31), 64 B/row,
//       16B-chunk c stored at physical chunk c ^ ((d>>1)&3)      [pre-swizzled]
//   P : slab (s, b, obx) -> 128 o-rows x 32 bf16, 64 B/row,
//       chunk c stored at physical chunk c ^ ((o_loc>>1)&3)      [pre-swizzled]
//  A wave's 4-frag read (16 rows x 4 chunks) is a contiguous, fully-coalesced 1 KB
//  block; (row>>1)&3 == (m16>>1)&3 is a per-lane constant.  gemm_kernel loads
//  fragments DIRECTLY global->VGPR (no LDS, no barriers) with a 4-deep register
//  pipeline (load->use distance = 3 MFMA blocks) to cover L2/LLC latency.
// =====================================================================================

// ------- weight reorder+cast, step-linear + chunk-swizzled -------
__global__ __launch_bounds__(256)
void reorder_w2_kernel(const float* __restrict__ w, uint32_t* __restrict__ Wr) {
    const int d   = blockIdx.x;
    const int tid = threadIdx.x;
    __shared__ float wrow[3584];
    const float4* src = (const float4*)(w + (size_t)d * 3584);
    for (int e = tid; e < 896; e += 256) ((float4*)wrow)[e] = src[e];
    __syncthreads();
    const int cc  = tid >> 4;
    const int clp = tid & 15;                                   // pair index in chunk (ch 2clp,2clp+1)
    const int pos = (((clp >> 2) ^ ((d >> 1) & 3)) << 2) | (clp & 3);
    #pragma unroll
    for (int k = 0; k < K_; ++k) {
        const float w0 = wrow[tid * 14 + k];
        const float w1 = wrow[tid * 14 + 7 + k];
        Wr[((size_t)(cc * 7 + k) * 512 + d) * 16 + pos] = (f2bf(w1) << 16) | f2bf(w0);
    }
}

// ------- interp+pack: stage x slab -> LDS, interpolate ONCE, write MFMA-ready P -------
__global__ __launch_bounds__(256)
void interp_pack_kernel(const float* __restrict__ x, const float* __restrict__ offs,
                        uint32_t* __restrict__ P) {
    const int obx = blockIdx.x;   // 0..31
    const int cc  = blockIdx.y;   // 0..15
    const int b   = blockIdx.z;
    const int tid = threadIdx.x;
    const int o0  = obx * 128;
    __shared__ __align__(16) uint32_t XT[2176];   // 136 cols x 16 pair-slots (XOR-swizzled)

    // ---- phase 1: x -> XT (bf16 channel-pairs, per-column XOR on pair-group) ----
    const float* xc = x + ((size_t)b * CIN + cc * 32) * L_ + o0;
    #pragma unroll
    for (int r = 0; r < 3; ++r) {
        const int e = r * 256 + tid;
        if (e < 544) {
            const int cp   = e / 34;
            const int col4 = e - cp * 34;
            const int colb = col4 * 4;
            const float* p0 = xc + (size_t)(2 * cp) * L_ + colb;
            const float* p1 = p0 + L_;
            float4 v0, v1;
            if (o0 + colb + 3 < L_) {
                v0 = *(const float4*)p0;
                v1 = *(const float4*)p1;
            } else {
                float a0 = (o0 + colb + 0 < L_) ? p0[0] : 0.f;
                float a1 = (o0 + colb + 1 < L_) ? p0[1] : 0.f;
                float a2 = (o0 + colb + 2 < L_) ? p0[2] : 0.f;
                float a3 = (o0 + colb + 3 < L_) ? p0[3] : 0.f;
                float b0 = (o0 + colb + 0 < L_) ? p1[0] : 0.f;
                float b1 = (o0 + colb + 1 < L_) ? p1[1] : 0.f;
                float b2 = (o0 + colb + 2 < L_) ? p1[2] : 0.f;
                float b3 = (o0 + colb + 3 < L_) ? p1[3] : 0.f;
                v0 = make_float4(a0, a1, a2, a3);
                v1 = make_float4(b0, b1, b2, b3);
            }
            const float* f0 = (const float*)&v0;
            const float* f1 = (const float*)&v1;
            const int cpg = cp >> 1, hh = cp & 1;
            #pragma unroll
            for (int ii = 0; ii < 4; ++ii) {
                const int col = colb + ii;
                XT[col * 16 + (((cpg ^ (col & 7)) << 1) | hh)] = pack2bf(f0[ii], f1[ii]);
            }
        }
    }
    __syncthreads();

    // ---- phase 2: interpolate, write P slabs (chunk-swizzled for coalesced reads) ----
    const int o_loc = tid >> 1;
    const int h     = tid & 1;                    // channel half: pairs 8h..8h+7
    int o = o0 + o_loc; if (o > OUT_LEN - 1) o = OUT_LEN - 1;
    const float t0f = (float)o;
    const int sr = (o_loc >> 1) & 3;
    uint32_t* Pb = P + ((size_t)((b * 16 + cc) * 7) * 32 + obx) * 2048 + o_loc * 16;
    const int c0 = ((2 * h) ^ sr) << 2;
    const int c1 = ((2 * h + 1) ^ sr) << 2;
    #pragma unroll
    for (int k = 0; k < K_; ++k) {
        const float off = offs[((size_t)b * OUT_LEN + o) * K_ + k];
        float T = t0f + (float)k + off;
        T = fmaxf(T, t0f);
        T = fminf(T, t0f + 6.0f);
        int u0 = (int)floorf(T); if (u0 > L_ - 2) u0 = L_ - 2;
        const float g1 = T - (float)u0;           // == max(0,1-|u0+1-T|)
        const float g0 = 1.0f - g1;               // == max(0,1-|u0-T|)
        const int ul = u0 - o0;
        const uint32_t* R0 = &XT[ul * 16];
        const uint32_t* R1 = &XT[(ul + 1) * 16];
        const int s0 = ul & 7, s1 = (ul + 1) & 7;
        uint32_t ow[8];
        #pragma unroll
        for (int q = 0; q < 4; ++q) {
            const int pg = h * 4 + q;             // pair-group -> pairs 2pg,2pg+1
            const uint2 lo = *(const uint2*)&R0[(pg ^ s0) << 1];
            const uint2 hi = *(const uint2*)&R1[(pg ^ s1) << 1];
            ow[q * 2 + 0] = interp1(lo.x, hi.x, g0, g1);
            ow[q * 2 + 1] = interp1(lo.y, hi.y, g0, g1);
        }
        uint32_t* Pk = Pb + (size_t)k * 65536;    // next k-slab: 32 slabs * 2048 u32
        *(uint4*)&Pk[c0] = make_uint4(ow[0], ow[1], ow[2], ow[3]);
        *(uint4*)&Pk[c1] = make_uint4(ow[4], ow[5], ow[6], ow[7]);
    }
}

// ------- zero-LDS, zero-barrier, 4-deep register-pipelined bf16 GEMM -------
__global__ __launch_bounds__(256, 2)
void gemm_kernel(const ushort_t* __restrict__ Wr, const uint32_t* __restrict__ P,
                 const float* __restrict__ bias, float* __restrict__ out) {
    const int bxi  = blockIdx.x;
    const int o0   = bxi * 128;
    const int d0   = blockIdx.y * 128;
    const int b    = blockIdx.z;
    const int tid  = threadIdx.x;
    const int wv   = tid >> 6;
    const int lane = tid & 63;
    const int m16  = lane & 15;
    const int quad = lane >> 4;
    const int wd   = wv >> 1;                     // d-half of wave
    const int wo   = wv & 1;                      // o-half of wave
    const int sw   = (m16 >> 1) & 3;              // == (row>>1)&3 for every fragment row
    const int chk  = quad ^ sw;                   // physical 16B chunk

    // lane base addresses; frag (i,s): Ab + s*16384 + i*512 (ushort units)
    const ushort_t* Ab = Wr + (size_t)(d0 + wd * 64 + m16) * 32 + chk * 8;
    // frag (j,s): Bb + s*65536 + j*256 (u32 units)
    const uint32_t* Bb = P + ((size_t)(b * 112) * 32 + bxi) * 2048
                           + (wo * 64 + m16) * 16 + chk * 4;

#define LDF(AF, BF, S)                                                        \
    { _Pragma("unroll")                                                       \
      for (int i_ = 0; i_ < 4; ++i_)                                          \
          AF[i_] = *(const bf16x8*)(Ab + (size_t)(S) * 16384 + i_ * 512);     \
      _Pragma("unroll")                                                       \
      for (int j_ = 0; j_ < 4; ++j_)                                          \
          BF[j_] = *(const bf16x8*)(Bb + (size_t)(S) * 65536 + j_ * 256); }

#define MFMA16(AF, BF)                                                        \
    { __builtin_amdgcn_s_setprio(1);                                          \
      _Pragma("unroll")                                                       \
      for (int i_ = 0; i_ < 4; ++i_) {                                        \
          _Pragma("unroll")                                                   \
          for (int j_ = 0; j_ < 4; ++j_)                                      \
              acc[i_][j_] = __builtin_amdgcn_mfma_f32_16x16x32_bf16(          \
                  AF[i_], BF[j_], acc[i_][j_], 0, 0, 0);                      \
      }                                                                       \
      __builtin_amdgcn_s_setprio(0); }

    f32x4 acc[4][4];
    #pragma unroll
    for (int i = 0; i < 4; ++i) {
        #pragma unroll
        for (int j = 0; j < 4; ++j) acc[i][j] = (f32x4){0.f, 0.f, 0.f, 0.f};
    }

    // 4 fragment sets, all statically indexed (named) to keep them in registers
    bf16x8 a0[4], b0v[4], a1[4], b1v[4], a2[4], b2v[4], a3[4], b3v[4];

    LDF(a0, b0v, 0);
    LDF(a1, b1v, 1);
    LDF(a2, b2v, 2);

    // steady state: load->use distance = 3 MFMA blocks for every set
    #pragma unroll 1
    for (int s = 0; s < 108; s += 4) {
        LDF(a3, b3v, s + 3); MFMA16(a0, b0v);
        LDF(a0, b0v, s + 4); MFMA16(a1, b1v);
        LDF(a1, b1v, s + 5); MFMA16(a2, b2v);
        LDF(a2, b2v, s + 6); MFMA16(a3, b3v);
    }
    // tail: steps 108..111 (108,109,110 already in a0/a1/a2)
    LDF(a3, b3v, 111);
    MFMA16(a0, b0v);
    MFMA16(a1, b1v);
    MFMA16(a2, b2v);
    MFMA16(a3, b3v);

    // epilogue (verified C/D layout: col=o (m16), row=quad*4+r on the d dim)
    #pragma unroll
    for (int i = 0; i < 4; ++i) {
        const int dd = d0 + wd * 64 + i * 16 + quad * 4;
        float bv[4];
        #pragma unroll
        for (int r = 0; r < 4; ++r) bv[r] = bias[dd + r];
        #pragma unroll
        for (int j = 0; j < 4; ++j) {
            const int oo = o0 + wo * 64 + j * 16 + m16;
            if (oo < OUT_LEN) {
                float* op = out + (size_t)b * COUT * OUT_LEN + (size_t)dd * OUT_LEN + oo;
                #pragma unroll
                for (int r = 0; r < 4; ++r)
                    op[(size_t)r * OUT_LEN] = acc[i][j][r] + bv[r];
            }
        }
    }
#undef LDF
#undef MFMA16
}

// =====================================================================================
//  OLD PATH (verified @186.9us) — used when ws is too small for P (117 MB)
// =====================================================================================

__global__ __launch_bounds__(256)
void reorder_w1_kernel(const float* __restrict__ w, uint32_t* __restrict__ Wr) {
    const int d   = blockIdx.x;
    const int tid = threadIdx.x;
    __shared__ float wrow[3584];
    const float4* src = (const float4*)(w + (size_t)d * 3584);
    for (int e = tid; e < 896; e += 256) ((float4*)wrow)[e] = src[e];
    __syncthreads();
    const int cc  = tid >> 4;
    const int clp = tid & 15;
    #pragma unroll
    for (int k = 0; k < K_; ++k) {
        const float w0 = wrow[tid * 14 + k];
        const float w1 = wrow[tid * 14 + 7 + k];
        Wr[((size_t)((k * 16 + cc) * 512 + d)) * 16 + clp] = (f2bf(w1) << 16) | f2bf(w0);
    }
}

__global__ __launch_bounds__(256)
void prepack_kernel(const float* __restrict__ x, uint32_t* __restrict__ xpack) {
    const int obx = blockIdx.x;   // 0..31
    const int cc  = blockIdx.y;   // 0..15
    const int b   = blockIdx.z;
    const int tid = threadIdx.x;
    const int o0  = obx * 128;
    __shared__ __align__(16) uint32_t XT[2176];
    const float* xc = x + ((size_t)b * CIN + cc * 32) * L_ + o0;
    #pragma unroll
    for (int r = 0; r < 3; ++r) {
        const int e = r * 256 + tid;
        if (e < 544) {
            const int cp   = e / 34;
            const int col4 = e - cp * 34;
            const int colb = col4 * 4;
            const float* p0 = xc + (size_t)(2 * cp) * L_ + colb;
            const float* p1 = p0 + L_;
            float4 v0, v1;
            if (o0 + colb + 3 < L_) {
                v0 = *(const float4*)p0;
                v1 = *(const float4*)p1;
            } else {
                float a0 = (o0 + colb + 0 < L_) ? p0[0] : 0.f;
                float a1 = (o0 + colb + 1 < L_) ? p0[1] : 0.f;
                float a2 = (o0 + colb + 2 < L_) ? p0[2] : 0.f;
                float a3 = (o0 + colb + 3 < L_) ? p0[3] : 0.f;
                float b0 = (o0 + colb + 0 < L_) ? p1[0] : 0.f;
                float b1 = (o0 + colb + 1 < L_) ? p1[1] : 0.f;
                float b2 = (o0 + colb + 2 < L_) ? p1[2] : 0.f;
                float b3 = (o0 + colb + 3 < L_) ? p1[3] : 0.f;
                v0 = make_float4(a0, a1, a2, a3);
                v1 = make_float4(b0, b1, b2, b3);
            }
            const float* f0 = (const float*)&v0;
            const float* f1 = (const float*)&v1;
            const int cpg = cp >> 1, h = cp & 1;
            #pragma unroll
            for (int ii = 0; ii < 4; ++ii) {
                const int col = colb + ii;
                XT[col * 16 + (((cpg ^ (col & 7)) << 1) | h)] = pack2bf(f0[ii], f1[ii]);
            }
        }
    }
    __syncthreads();
    uint4* dst = (uint4*)xpack + (size_t)((b * 16 + cc) * 32 + obx) * 544;
    const uint4* s4 = (const uint4*)XT;
    #pragma unroll
    for (int r = 0; r < 3; ++r) {
        const int e = r * 256 + tid;
        if (e < 544) dst[e] = s4[e];
    }
}

__global__ __launch_bounds__(256, 2)
void fused_v1_kernel(const float* __restrict__ offs, const ushort_t* __restrict__ Wr,
                     const uint32_t* __restrict__ xpack, const float* __restrict__ bias,
                     float* __restrict__ out) {
    const int bxi  = blockIdx.x;
    const int o0   = bxi * 128;
    const int d0   = blockIdx.y * 128;
    const int b    = blockIdx.z;
    const int tid  = threadIdx.x;
    const int wv   = tid >> 6;
    const int lane = tid & 63;
    const int m16  = lane & 15;
    const int quad = lane >> 4;
    const int ob   = wv * 32;
    const int q2   = quad * 2;

    __shared__ __align__(16) ushort_t As0[4096], As1[4096], As2[4096], As3[4096];
    __shared__ __align__(16) uint32_t XTB0[2304], XTB1[2304];
    __shared__ int    SU[896];
    __shared__ float2 PG[896];

#define ISSUE_A(KK, CC, ASP)                                                      \
    {                                                                             \
        _Pragma("unroll")                                                         \
        for (int r_ = 0; r_ < 2; ++r_) {                                          \
            const int c_ = r_ * 256 + tid;                                        \
            const int row_ = c_ >> 2, pc_ = c_ & 3;                               \
            const ushort_t* g_ = Wr                                               \
                + ((size_t)(((KK) * 16 + (CC)) * 512 + d0 + row_)) * 32 + pc_ * 8;\
            async16(g_, (void*)((ASP) + (r_ * 256 + wv * 64) * 8));               \
        }                                                                         \
    }

#define ISSUE_XTB(CC, XP)                                                         \
    {                                                                             \
        const uint32_t* sp_ = xpack + ((size_t)((b * 16 + (CC)) * 32 + bxi)) * 2176; \
        _Pragma("unroll")                                                         \
        for (int r_ = 0; r_ < 3; ++r_) {                                          \
            const int cb_ = r_ * 256 + wv * 64;                                   \
            if (cb_ < 544) {                                                      \
                const int c_ = r_ * 256 + tid;                                    \
                async16((const void*)(sp_ + (size_t)c_ * 4),                      \
                        (void*)((XP) + (size_t)cb_ * 4));                         \
            }                                                                     \
        }                                                                         \
    }

#define STEP(KK, XP, ASP)                                                         \
    {                                                                             \
        bf16x8 af_[8];                                                            \
        _Pragma("unroll")                                                         \
        for (int i_ = 0; i_ < 8; ++i_)                                            \
            af_[i_] = *(const bf16x8*)&(ASP)[(i_ * 16 + m16) * 32 + quad * 8];    \
        bf16x8 bfr_[2];                                                           \
        _Pragma("unroll")                                                         \
        for (int j_ = 0; j_ < 2; ++j_) {                                          \
            const int row_ = ((KK) << 7) | (ob + j_ * 16 + m16);                  \
            const int u_ = SU[row_];                                              \
            const float2 g_ = PG[row_];                                           \
            const uint32_t* Xr0_ = &(XP)[u_ * 16];                                \
            const uint32_t* Xr1_ = Xr0_ + 16;                                     \
            const int s0_ = u_ & 7, s1_ = (u_ + 1) & 7;                           \
            const uint2 a0_ = *(const uint2*)&Xr0_[((q2     ^ s0_) << 1)];        \
            const uint2 a1_ = *(const uint2*)&Xr0_[(((q2+1) ^ s0_) << 1)];        \
            const uint2 c0_ = *(const uint2*)&Xr1_[((q2     ^ s1_) << 1)];        \
            const uint2 c1_ = *(const uint2*)&Xr1_[(((q2+1) ^ s1_) << 1)];        \
            uint4 rr_;                                                            \
            rr_.x = interp1(a0_.x, c0_.x, g_.x, g_.y);                            \
            rr_.y = interp1(a0_.y, c0_.y, g_.x, g_.y);                            \
            rr_.z = interp1(a1_.x, c1_.x, g_.x, g_.y);                            \
            rr_.w = interp1(a1_.y, c1_.y, g_.x, g_.y);                            \
            __builtin_memcpy(&bfr_[j_], &rr_, 16);                                \
        }                                                                         \
        _Pragma("unroll")                                                         \
        for (int i_ = 0; i_ < 8; ++i_) {                                          \
            _Pragma("unroll")                                                     \
            for (int j_ = 0; j_ < 2; ++j_)                                        \
                acc[i_][j_] = __builtin_amdgcn_mfma_f32_16x16x32_bf16(af_[i_], bfr_[j_], acc[i_][j_], 0, 0, 0); \
        }                                                                         \
    }

#define HALF(CCB, A0_, A1_, A2_, A3_)                                             \
    ISSUE_A(2, (CCB), A2_); ISSUE_A(3, (CCB), A3_); ISSUE_XTB((CCB) + 1, XTB1);   \
    STEP(0, XTB0, A0_); STEP(1, XTB0, A1_); __syncthreads();                      \
    ISSUE_A(4, (CCB), A0_); ISSUE_A(5, (CCB), A1_);                               \
    STEP(2, XTB0, A2_); STEP(3, XTB0, A3_); __syncthreads();                      \
    ISSUE_A(6, (CCB), A2_); ISSUE_A(0, (CCB) + 1, A3_);                           \
    STEP(4, XTB0, A0_); STEP(5, XTB0, A1_); __syncthreads();                      \
    ISSUE_A(1, (CCB) + 1, A0_); ISSUE_A(2, (CCB) + 1, A1_);                       \
    STEP(6, XTB0, A2_); STEP(0, XTB1, A3_); __syncthreads();                      \
    ISSUE_A(3, (CCB) + 1, A2_); ISSUE_A(4, (CCB) + 1, A3_);                       \
    if ((CCB) + 2 < 16) { ISSUE_XTB((CCB) + 2, XTB0); }                           \
    STEP(1, XTB1, A0_); STEP(2, XTB1, A1_); __syncthreads();                      \
    ISSUE_A(5, (CCB) + 1, A0_); ISSUE_A(6, (CCB) + 1, A1_);                       \
    STEP(3, XTB1, A2_); STEP(4, XTB1, A3_); __syncthreads();                      \
    if ((CCB) + 2 < 16) { ISSUE_A(0, (CCB) + 2, A2_); ISSUE_A(1, (CCB) + 2, A3_); } \
    STEP(5, XTB1, A0_); STEP(6, XTB1, A1_); __syncthreads();

    f32x4 acc[8][2];
    #pragma unroll
    for (int i = 0; i < 8; ++i) {
        #pragma unroll
        for (int j = 0; j < 2; ++j) acc[i][j] = (f32x4){0.f, 0.f, 0.f, 0.f};
    }

    ISSUE_XTB(0, XTB0);
    ISSUE_A(0, 0, As0);
    ISSUE_A(1, 0, As1);
    for (int e = tid; e < 896; e += 256) {
        const int k  = e >> 7;
        const int ol = e & 127;
        int o = o0 + ol; if (o > OUT_LEN - 1) o = OUT_LEN - 1;
        const float t0  = (float)o;
        const float off = offs[((size_t)b * OUT_LEN + o) * K_ + k];
        float T = t0 + (float)k + off;
        T = fmaxf(T, t0);
        T = fminf(T, t0 + 6.0f);
        int u0 = (int)floorf(T);
        if (u0 > L_ - 2) u0 = L_ - 2;
        const float g0 = fmaxf(1.0f - fabsf((float)u0 - T), 0.0f);
        const float g1 = fmaxf(1.0f - fabsf((float)(u0 + 1) - T), 0.0f);
        SU[e] = u0 - o0;
        PG[e] = make_float2(g0, g1);
    }
    __syncthreads();

    #pragma unroll 1
    for (int s4 = 0; s4 < 16; s4 += 4) {
        HALF(s4,     As0, As1, As2, As3)
        HALF(s4 + 2, As2, As3, As0, As1)
    }

    #pragma unroll
    for (int i = 0; i < 8; ++i) {
        const int dd = d0 + i * 16 + quad * 4;
        float bv[4];
        #pragma unroll
        for (int r = 0; r < 4; ++r) bv[r] = bias[dd + r];
        #pragma unroll
        for (int j = 0; j < 2; ++j) {
            const int oo = o0 + ob + j * 16 + m16;
            if (oo < OUT_LEN) {
                float* op = out + (size_t)b * COUT * OUT_LEN + (size_t)dd * OUT_LEN + oo;
                #pragma unroll
                for (int r = 0; r < 4; ++r)
                    op[(size_t)r * OUT_LEN] = acc[i][j][r] + bv[r];
            }
        }
    }
#undef ISSUE_A
#undef ISSUE_XTB
#undef STEP
#undef HALF
}

// ---------------- fp32 fallback (round-1 kernel, used only if ws too small) ----------------
#define BM 64
#define BN 64
#define BC 8
#define TT (BC * K_)

__global__ __launch_bounds__(256, 2)
void deform_conv1d_fallback(const float* __restrict__ x, const float* __restrict__ offsets,
                            const float* __restrict__ weight, const float* __restrict__ bias,
                            float* __restrict__ out) {
    const int o0 = blockIdx.x * BN, d0 = blockIdx.y * BM, b = blockIdx.z, tid = threadIdx.x;
    __shared__ int   SU[BN * K_];
    __shared__ float SG0[BN * K_], SG1[BN * K_];
    __shared__ float XT[BC][BN + 8];
    __shared__ float S[BC][K_][BN];
    __shared__ float WT[BM][TT + 1];
    for (int e = tid; e < BN * K_; e += 256) {
        const int ol = e / K_, k = e % K_, o = o0 + ol;
        int u0rel = 0; float g0 = 0.f, g1 = 0.f;
        if (o < OUT_LEN) {
            const float t0 = (float)o;
            const float off = offsets[(size_t)b * OUT_LEN * K_ + (size_t)o * K_ + k];
            float T = fminf(fmaxf(t0 + (float)k + off, t0), t0 + 6.0f);
            int u0 = (int)floorf(T); if (u0 > L_ - 2) u0 = L_ - 2;
            g0 = fmaxf(1.0f - fabsf((float)u0 - T), 0.0f);
            g1 = fmaxf(1.0f - fabsf((float)(u0 + 1) - T), 0.0f);
            u0rel = u0 - o0;
        }
        SU[e] = u0rel; SG0[e] = g0; SG1[e] = g1;
    }
    float acc[4][4];
    #pragma unroll
    for (int i = 0; i < 4; ++i) {
        #pragma unroll
        for (int j = 0; j < 4; ++j) acc[i][j] = 0.f;
    }
    const int ty = tid >> 4, tx = tid & 15;
    const float* xb = x + (size_t)b * CIN * L_;
    for (int c0 = 0; c0 < CIN; c0 += BC) {
        __syncthreads();
        for (int e = tid; e < BC * (BN + 7); e += 256) {
            const int cl = e / (BN + 7), j = e % (BN + 7), pos = o0 + j;
            XT[cl][j] = (pos < L_) ? xb[(size_t)(c0 + cl) * L_ + pos] : 0.f;
        }
        for (int e = tid; e < BM * TT; e += 256) {
            const int d = e / TT, t = e % TT;
            WT[d][t] = weight[(size_t)(d0 + d) * (CIN * K_) + c0 * K_ + t];
        }
        __syncthreads();
        for (int e = tid; e < BC * K_ * BN; e += 256) {
            const int cl = e / (K_ * BN), r = e % (K_ * BN), k = r / BN, ol = r % BN;
            const int p = ol * K_ + k, u = SU[p];
            S[cl][k][ol] = SG0[p] * XT[cl][u] + SG1[p] * XT[cl][u + 1];
        }
        __syncthreads();
        #pragma unroll
        for (int t = 0; t < TT; ++t) {
            const int cl = t / K_, k = t % K_;
            const float4 s4 = *(const float4*)&S[cl][k][tx * 4];
            const float w0 = WT[ty * 4 + 0][t], w1 = WT[ty * 4 + 1][t];
            const float w2 = WT[ty * 4 + 2][t], w3 = WT[ty * 4 + 3][t];
            acc[0][0] += w0 * s4.x; acc[0][1] += w0 * s4.y; acc[0][2] += w0 * s4.z; acc[0][3] += w0 * s4.w;
            acc[1][0] += w1 * s4.x; acc[1][1] += w1 * s4.y; acc[1][2] += w1 * s4.z; acc[1][3] += w1 * s4.w;
            acc[2][0] += w2 * s4.x; acc[2][1] += w2 * s4.y; acc[2][2] += w2 * s4.z; acc[2][3] += w2 * s4.w;
            acc[3][0] += w3 * s4.x; acc[3][1] += w3 * s4.y; acc[3][2] += w3 * s4.z; acc[3][3] += w3 * s4.w;
        }
    }
    #pragma unroll
    for (int i = 0; i < 4; ++i) {
        const int d = d0 + ty * 4 + i;
        const float bvv = bias[d];
        #pragma unroll
        for (int j = 0; j < 4; ++j) {
            const int o = o0 + tx * 4 + j;
            if (o < OUT_LEN)
                out[(size_t)b * COUT * OUT_LEN + (size_t)d * OUT_LEN + o] = acc[i][j] + bvv;
        }
    }
}

extern "C" void kernel_launch(void* const* d_in, const int* in_sizes, int n_in,
                              void* d_out, int out_size, void* d_ws, size_t ws_size,
                              hipStream_t stream) {
    const float* x       = (const float*)d_in[0];
    const float* offsets = (const float*)d_in[1];
    const float* weight  = (const float*)d_in[2];
    const float* bias    = (const float*)d_in[3];
    float* out = (float*)d_out;

    const size_t WR_BYTES = (size_t)512 * 512 * 7 * 2;                  // 3,670,016
    const size_t P_BYTES  = (size_t)4 * 16 * 7 * 32 * 8192;             // 117,440,512
    const size_t XP_BYTES = (size_t)2048 * 544 * 16 + 512;              // 17,826,304

    if (ws_size >= WR_BYTES + P_BYTES) {
        // new path: precomputed interp + zero-LDS 4-deep register-pipelined GEMM
        uint32_t* Wr_u32 = (uint32_t*)d_ws;
        ushort_t* Wr     = (ushort_t*)d_ws;
        uint32_t* P      = (uint32_t*)((char*)d_ws + WR_BYTES);
        reorder_w2_kernel<<<512, 256, 0, stream>>>(weight, Wr_u32);
        interp_pack_kernel<<<dim3(32, 16, B_), 256, 0, stream>>>(x, offsets, P);
        gemm_kernel<<<dim3(32, 4, B_), 256, 0, stream>>>(Wr, P, bias, out);
        return;
    }

    if (ws_size >= WR_BYTES + XP_BYTES) {
        // old verified path
        uint32_t* Wr_u32 = (uint32_t*)d_ws;
        ushort_t* Wr     = (ushort_t*)d_ws;
        uint32_t* xpack  = (uint32_t*)((char*)d_ws + WR_BYTES);
        reorder_w1_kernel<<<512, 256, 0, stream>>>(weight, Wr_u32);
        prepack_kernel<<<dim3(32, 16, B_), 256, 0, stream>>>(x, xpack);
        fused_v1_kernel<<<dim3(32, 4, B_), 256, 0, stream>>>(offsets, Wr, xpack, bias, out);
        return;
    }

    dim3 grid((OUT_LEN + BN - 1) / BN, COUT / BM, B_);
    deform_conv1d_fallback<<<grid, 256, 0, stream>>>(x, offsets, weight, bias, out);
}

// Round 4
// 169.113 us; speedup vs baseline: 1.0785x; 1.0631x over previous
//
#include <hip/hip_runtime.h>
#include <hip/hip_bf16.h>
#include <stdint.h>

#define B_      4
#define CIN     512
#define COUT    512
#define L_      4096
#define K_      7
#define OUT_LEN 4090

typedef unsigned short ushort_t;
typedef __attribute__((ext_vector_type(8))) __bf16 bf16x8;
typedef __attribute__((ext_vector_type(4))) float f32x4;

__device__ __forceinline__ uint32_t f2bf(float f) {
    uint32_t u = __float_as_uint(f);
    return (u + 0x7fffu + ((u >> 16) & 1u)) >> 16;
}

__device__ __forceinline__ uint32_t pack2bf(float s0, float s1) {   // s0 -> low 16
    __hip_bfloat162 h = __float22bfloat162_rn(make_float2(s0, s1));
    uint32_t r;
    __builtin_memcpy(&r, &h, 4);
    return r;
}

__device__ __forceinline__ uint32_t interp1(uint32_t wl, uint32_t wh, float g0, float g1) {
    const float l0 = __uint_as_float(wl << 16);
    const float l1 = __uint_as_float(wl & 0xffff0000u);
    const float h0 = __uint_as_float(wh << 16);
    const float h1 = __uint_as_float(wh & 0xffff0000u);
    return pack2bf(g0 * l0 + g1 * h0, g0 * l1 + g1 * h1);
}

__device__ __forceinline__ void async16(const void* g, void* l) {
    __builtin_amdgcn_global_load_lds(
        (const __attribute__((address_space(1))) unsigned int*)g,
        (__attribute__((address_space(3))) unsigned int*)l, 16, 0, 0);
}

// =====================================================================================
//  NEW PATH
//  Layouts (step s = cc*7 + k, s = 0..111):
//   Wr: slab s -> 512 d-rows x 32 bf16 (channels cc*32..+31), 64 B/row,
//       16B-chunk c stored at physical chunk c ^ ((d>>1)&3)      [pre-swizzled]
//   P : slab (s, b, obx) -> 128 o-rows x 32 bf16, 64 B/row,
//       chunk c stored at physical chunk c ^ ((o_loc>>1)&3)      [pre-swizzled]
//  gemm: global_load_lds DMA into a 4-slab LDS rotation with COUNTED vmcnt(8)
//  (2 slabs always in flight across raw s_barriers -- T3/T4) so the ~800-cyc
//  LLC latency of P reads is hidden.  ds_read addressing identical to the
//  verified round-1 LDS kernel (0 bank conflicts).
// =====================================================================================

// ------- weight reorder+cast, step-linear + chunk-swizzled -------
__global__ __launch_bounds__(256)
void reorder_w2_kernel(const float* __restrict__ w, uint32_t* __restrict__ Wr) {
    const int d   = blockIdx.x;
    const int tid = threadIdx.x;
    __shared__ float wrow[3584];
    const float4* src = (const float4*)(w + (size_t)d * 3584);
    for (int e = tid; e < 896; e += 256) ((float4*)wrow)[e] = src[e];
    __syncthreads();
    const int cc  = tid >> 4;
    const int clp = tid & 15;                                   // pair index in chunk (ch 2clp,2clp+1)
    const int pos = (((clp >> 2) ^ ((d >> 1) & 3)) << 2) | (clp & 3);
    #pragma unroll
    for (int k = 0; k < K_; ++k) {
        const float w0 = wrow[tid * 14 + k];
        const float w1 = wrow[tid * 14 + 7 + k];
        Wr[((size_t)(cc * 7 + k) * 512 + d) * 16 + pos] = (f2bf(w1) << 16) | f2bf(w0);
    }
}

// ------- interp+pack: stage x slab -> LDS, interpolate ONCE, write MFMA-ready P -------
__global__ __launch_bounds__(256)
void interp_pack_kernel(const float* __restrict__ x, const float* __restrict__ offs,
                        uint32_t* __restrict__ P) {
    const int obx = blockIdx.x;   // 0..31
    const int cc  = blockIdx.y;   // 0..15
    const int b   = blockIdx.z;
    const int tid = threadIdx.x;
    const int o0  = obx * 128;
    __shared__ __align__(16) uint32_t XT[2176];   // 136 cols x 16 pair-slots (XOR-swizzled)

    // ---- phase 1: x -> XT (bf16 channel-pairs, per-column XOR on pair-group) ----
    const float* xc = x + ((size_t)b * CIN + cc * 32) * L_ + o0;
    #pragma unroll
    for (int r = 0; r < 3; ++r) {
        const int e = r * 256 + tid;
        if (e < 544) {
            const int cp   = e / 34;
            const int col4 = e - cp * 34;
            const int colb = col4 * 4;
            const float* p0 = xc + (size_t)(2 * cp) * L_ + colb;
            const float* p1 = p0 + L_;
            float4 v0, v1;
            if (o0 + colb + 3 < L_) {
                v0 = *(const float4*)p0;
                v1 = *(const float4*)p1;
            } else {
                float a0 = (o0 + colb + 0 < L_) ? p0[0] : 0.f;
                float a1 = (o0 + colb + 1 < L_) ? p0[1] : 0.f;
                float a2 = (o0 + colb + 2 < L_) ? p0[2] : 0.f;
                float a3 = (o0 + colb + 3 < L_) ? p0[3] : 0.f;
                float b0 = (o0 + colb + 0 < L_) ? p1[0] : 0.f;
                float b1 = (o0 + colb + 1 < L_) ? p1[1] : 0.f;
                float b2 = (o0 + colb + 2 < L_) ? p1[2] : 0.f;
                float b3 = (o0 + colb + 3 < L_) ? p1[3] : 0.f;
                v0 = make_float4(a0, a1, a2, a3);
                v1 = make_float4(b0, b1, b2, b3);
            }
            const float* f0 = (const float*)&v0;
            const float* f1 = (const float*)&v1;
            const int cpg = cp >> 1, hh = cp & 1;
            #pragma unroll
            for (int ii = 0; ii < 4; ++ii) {
                const int col = colb + ii;
                XT[col * 16 + (((cpg ^ (col & 7)) << 1) | hh)] = pack2bf(f0[ii], f1[ii]);
            }
        }
    }
    __syncthreads();

    // ---- phase 2: interpolate, write P slabs (chunk-swizzled for coalesced reads) ----
    const int o_loc = tid >> 1;
    const int h     = tid & 1;                    // channel half: pairs 8h..8h+7
    int o = o0 + o_loc; if (o > OUT_LEN - 1) o = OUT_LEN - 1;
    const float t0f = (float)o;
    const int sr = (o_loc >> 1) & 3;
    uint32_t* Pb = P + ((size_t)((b * 16 + cc) * 7) * 32 + obx) * 2048 + o_loc * 16;
    const int c0 = ((2 * h) ^ sr) << 2;
    const int c1 = ((2 * h + 1) ^ sr) << 2;
    #pragma unroll
    for (int k = 0; k < K_; ++k) {
        const float off = offs[((size_t)b * OUT_LEN + o) * K_ + k];
        float T = t0f + (float)k + off;
        T = fmaxf(T, t0f);
        T = fminf(T, t0f + 6.0f);
        int u0 = (int)floorf(T); if (u0 > L_ - 2) u0 = L_ - 2;
        const float g1 = T - (float)u0;           // == max(0,1-|u0+1-T|)
        const float g0 = 1.0f - g1;               // == max(0,1-|u0-T|)
        const int ul = u0 - o0;
        const uint32_t* R0 = &XT[ul * 16];
        const uint32_t* R1 = &XT[(ul + 1) * 16];
        const int s0 = ul & 7, s1 = (ul + 1) & 7;
        uint32_t ow[8];
        #pragma unroll
        for (int q = 0; q < 4; ++q) {
            const int pg = h * 4 + q;             // pair-group -> pairs 2pg,2pg+1
            const uint2 lo = *(const uint2*)&R0[(pg ^ s0) << 1];
            const uint2 hi = *(const uint2*)&R1[(pg ^ s1) << 1];
            ow[q * 2 + 0] = interp1(lo.x, hi.x, g0, g1);
            ow[q * 2 + 1] = interp1(lo.y, hi.y, g0, g1);
        }
        uint32_t* Pk = Pb + (size_t)k * 65536;    // next k-slab: 32 slabs * 2048 u32
        *(uint4*)&Pk[c0] = make_uint4(ow[0], ow[1], ow[2], ow[3]);
        *(uint4*)&Pk[c1] = make_uint4(ow[4], ow[5], ow[6], ow[7]);
    }
}

// ------- DMA-fed GEMM with counted-vmcnt 4-slab pipeline (raw barriers, no drain) ----
__global__ __launch_bounds__(256, 2)
void gemm_kernel(const ushort_t* __restrict__ Wr, const uint32_t* __restrict__ P,
                 const float* __restrict__ bias, float* __restrict__ out) {
    const int bxi  = blockIdx.x;
    const int o0   = bxi * 128;
    const int d0   = blockIdx.y * 128;
    const int b    = blockIdx.z;
    const int tid  = threadIdx.x;
    const int wv   = tid >> 6;
    const int lane = tid & 63;
    const int m16  = lane & 15;
    const int quad = lane >> 4;
    const int wd   = wv >> 1;                     // d-half of wave
    const int wo   = wv & 1;                      // o-half of wave
    const int sw   = (m16 >> 1) & 3;              // == (row>>1)&3 for every fragment row
    const int chk  = (quad ^ sw) * 8;             // physical 16B chunk (ushort units)

    __shared__ __align__(16) ushort_t As0[4096], As1[4096], As2[4096], As3[4096];
    __shared__ __align__(16) ushort_t Bs0[4096], Bs1[4096], Bs2[4096], Bs3[4096];

    const int aoff = (wd * 64 + m16) * 32 + chk;
    const int boff = (wo * 64 + m16) * 32 + chk;

    const ushort_t* Ag = Wr + (size_t)d0 * 32 + (size_t)tid * 8;                      // +s*16384
    const uint32_t* Bg = P + ((size_t)(b * 112) * 32 + bxi) * 2048 + (size_t)tid * 4; // +s*65536

// 4 global_load_lds per wave per slab-step (2 A + 2 B)
#define ISSUE(S, ASP, BSP)                                                    \
    { _Pragma("unroll") for (int r_ = 0; r_ < 2; ++r_)                        \
        async16(Ag + (size_t)(S) * 16384 + r_ * 2048,                         \
                (void*)((ASP) + (r_ * 256 + wv * 64) * 8));                   \
      _Pragma("unroll") for (int r_ = 0; r_ < 2; ++r_)                        \
        async16(Bg + (size_t)(S) * 65536 + r_ * 1024,                         \
                (void*)((BSP) + (r_ * 256 + wv * 64) * 8)); }

// counted wait: N vmem ops may remain in flight (8 = 2 slabs), then raw barrier.
// sched_barrier(0) pins: nothing below (ds_read/MFMA) may be hoisted above.
#define WAITBAR(N)                                                            \
    { asm volatile("s_waitcnt vmcnt(" #N ")" ::: "memory");                   \
      __builtin_amdgcn_s_barrier();                                           \
      __builtin_amdgcn_sched_barrier(0); }

#define SSTEP(ASP, BSP)                                                       \
    {                                                                         \
        bf16x8 af_[4], bf_[4];                                                \
        _Pragma("unroll")                                                     \
        for (int i_ = 0; i_ < 4; ++i_) af_[i_] = *(const bf16x8*)&(ASP)[aoff + i_ * 512]; \
        _Pragma("unroll")                                                     \
        for (int j_ = 0; j_ < 4; ++j_) bf_[j_] = *(const bf16x8*)&(BSP)[boff + j_ * 512]; \
        __builtin_amdgcn_s_setprio(1);                                        \
        _Pragma("unroll")                                                     \
        for (int i_ = 0; i_ < 4; ++i_) {                                      \
            _Pragma("unroll")                                                 \
            for (int j_ = 0; j_ < 4; ++j_)                                    \
                acc[i_][j_] = __builtin_amdgcn_mfma_f32_16x16x32_bf16(        \
                    af_[i_], bf_[j_], acc[i_][j_], 0, 0, 0);                  \
        }                                                                     \
        __builtin_amdgcn_s_setprio(0);                                        \
    }

    f32x4 acc[4][4];
    #pragma unroll
    for (int i = 0; i < 4; ++i) {
        #pragma unroll
        for (int j = 0; j < 4; ++j) acc[i][j] = (f32x4){0.f, 0.f, 0.f, 0.f};
    }

    // prologue: slabs 0,1 in flight (8 vmem ops/wave)
    ISSUE(0, As0, Bs0);
    ISSUE(1, As1, Bs1);

    // steady state: unroll-by-4 keeps buffer indices static; vmcnt(8) keeps
    // 2 slabs in flight across every barrier (never drains to 0).
    // WAR safety: a buffer is re-targeted only >=2 barriers after its last read.
    #pragma unroll 1
    for (int t = 0; t < 108; t += 4) {
        ISSUE(t + 2, As2, Bs2); WAITBAR(8); SSTEP(As0, Bs0);
        ISSUE(t + 3, As3, Bs3); WAITBAR(8); SSTEP(As1, Bs1);
        ISSUE(t + 4, As0, Bs0); WAITBAR(8); SSTEP(As2, Bs2);
        ISSUE(t + 5, As1, Bs1); WAITBAR(8); SSTEP(As3, Bs3);
    }
    // peel: steps 108..111 (slabs 108,109 in flight; 110,111 still to issue)
    ISSUE(110, As2, Bs2); WAITBAR(8); SSTEP(As0, Bs0);   // step 108
    ISSUE(111, As3, Bs3); WAITBAR(8); SSTEP(As1, Bs1);   // step 109
    WAITBAR(4); SSTEP(As2, Bs2);                          // step 110
    WAITBAR(0); SSTEP(As3, Bs3);                          // step 111

    // epilogue (verified C/D layout: col=o (m16), row=quad*4+r on the d dim)
    #pragma unroll
    for (int i = 0; i < 4; ++i) {
        const int dd = d0 + wd * 64 + i * 16 + quad * 4;
        float bv[4];
        #pragma unroll
        for (int r = 0; r < 4; ++r) bv[r] = bias[dd + r];
        #pragma unroll
        for (int j = 0; j < 4; ++j) {
            const int oo = o0 + wo * 64 + j * 16 + m16;
            if (oo < OUT_LEN) {
                float* op = out + (size_t)b * COUT * OUT_LEN + (size_t)dd * OUT_LEN + oo;
                #pragma unroll
                for (int r = 0; r < 4; ++r)
                    op[(size_t)r * OUT_LEN] = acc[i][j][r] + bv[r];
            }
        }
    }
#undef ISSUE
#undef WAITBAR
#undef SSTEP
}

// =====================================================================================
//  OLD PATH (verified @186.9us) — used when ws is too small for P (117 MB)
// =====================================================================================

__global__ __launch_bounds__(256)
void reorder_w1_kernel(const float* __restrict__ w, uint32_t* __restrict__ Wr) {
    const int d   = blockIdx.x;
    const int tid = threadIdx.x;
    __shared__ float wrow[3584];
    const float4* src = (const float4*)(w + (size_t)d * 3584);
    for (int e = tid; e < 896; e += 256) ((float4*)wrow)[e] = src[e];
    __syncthreads();
    const int cc  = tid >> 4;
    const int clp = tid & 15;
    #pragma unroll
    for (int k = 0; k < K_; ++k) {
        const float w0 = wrow[tid * 14 + k];
        const float w1 = wrow[tid * 14 + 7 + k];
        Wr[((size_t)((k * 16 + cc) * 512 + d)) * 16 + clp] = (f2bf(w1) << 16) | f2bf(w0);
    }
}

__global__ __launch_bounds__(256)
void prepack_kernel(const float* __restrict__ x, uint32_t* __restrict__ xpack) {
    const int obx = blockIdx.x;   // 0..31
    const int cc  = blockIdx.y;   // 0..15
    const int b   = blockIdx.z;
    const int tid = threadIdx.x;
    const int o0  = obx * 128;
    __shared__ __align__(16) uint32_t XT[2176];
    const float* xc = x + ((size_t)b * CIN + cc * 32) * L_ + o0;
    #pragma unroll
    for (int r = 0; r < 3; ++r) {
        const int e = r * 256 + tid;
        if (e < 544) {
            const int cp   = e / 34;
            const int col4 = e - cp * 34;
            const int colb = col4 * 4;
            const float* p0 = xc + (size_t)(2 * cp) * L_ + colb;
            const float* p1 = p0 + L_;
            float4 v0, v1;
            if (o0 + colb + 3 < L_) {
                v0 = *(const float4*)p0;
                v1 = *(const float4*)p1;
            } else {
                float a0 = (o0 + colb + 0 < L_) ? p0[0] : 0.f;
                float a1 = (o0 + colb + 1 < L_) ? p0[1] : 0.f;
                float a2 = (o0 + colb + 2 < L_) ? p0[2] : 0.f;
                float a3 = (o0 + colb + 3 < L_) ? p0[3] : 0.f;
                float b0 = (o0 + colb + 0 < L_) ? p1[0] : 0.f;
                float b1 = (o0 + colb + 1 < L_) ? p1[1] : 0.f;
                float b2 = (o0 + colb + 2 < L_) ? p1[2] : 0.f;
                float b3 = (o0 + colb + 3 < L_) ? p1[3] : 0.f;
                v0 = make_float4(a0, a1, a2, a3);
                v1 = make_float4(b0, b1, b2, b3);
            }
            const float* f0 = (const float*)&v0;
            const float* f1 = (const float*)&v1;
            const int cpg = cp >> 1, h = cp & 1;
            #pragma unroll
            for (int ii = 0; ii < 4; ++ii) {
                const int col = colb + ii;
                XT[col * 16 + (((cpg ^ (col & 7)) << 1) | h)] = pack2bf(f0[ii], f1[ii]);
            }
        }
    }
    __syncthreads();
    uint4* dst = (uint4*)xpack + (size_t)((b * 16 + cc) * 32 + obx) * 544;
    const uint4* s4 = (const uint4*)XT;
    #pragma unroll
    for (int r = 0; r < 3; ++r) {
        const int e = r * 256 + tid;
        if (e < 544) dst[e] = s4[e];
    }
}

__global__ __launch_bounds__(256, 2)
void fused_v1_kernel(const float* __restrict__ offs, const ushort_t* __restrict__ Wr,
                     const uint32_t* __restrict__ xpack, const float* __restrict__ bias,
                     float* __restrict__ out) {
    const int bxi  = blockIdx.x;
    const int o0   = bxi * 128;
    const int d0   = blockIdx.y * 128;
    const int b    = blockIdx.z;
    const int tid  = threadIdx.x;
    const int wv   = tid >> 6;
    const int lane = tid & 63;
    const int m16  = lane & 15;
    const int quad = lane >> 4;
    const int ob   = wv * 32;
    const int q2   = quad * 2;

    __shared__ __align__(16) ushort_t As0[4096], As1[4096], As2[4096], As3[4096];
    __shared__ __align__(16) uint32_t XTB0[2304], XTB1[2304];
    __shared__ int    SU[896];
    __shared__ float2 PG[896];

#define ISSUE_A(KK, CC, ASP)                                                      \
    {                                                                             \
        _Pragma("unroll")                                                         \
        for (int r_ = 0; r_ < 2; ++r_) {                                          \
            const int c_ = r_ * 256 + tid;                                        \
            const int row_ = c_ >> 2, pc_ = c_ & 3;                               \
            const ushort_t* g_ = Wr                                               \
                + ((size_t)(((KK) * 16 + (CC)) * 512 + d0 + row_)) * 32 + pc_ * 8;\
            async16(g_, (void*)((ASP) + (r_ * 256 + wv * 64) * 8));               \
        }                                                                         \
    }

#define ISSUE_XTB(CC, XP)                                                         \
    {                                                                             \
        const uint32_t* sp_ = xpack + ((size_t)((b * 16 + (CC)) * 32 + bxi)) * 2176; \
        _Pragma("unroll")                                                         \
        for (int r_ = 0; r_ < 3; ++r_) {                                          \
            const int cb_ = r_ * 256 + wv * 64;                                   \
            if (cb_ < 544) {                                                      \
                const int c_ = r_ * 256 + tid;                                    \
                async16((const void*)(sp_ + (size_t)c_ * 4),                      \
                        (void*)((XP) + (size_t)cb_ * 4));                         \
            }                                                                     \
        }                                                                         \
    }

#define STEP(KK, XP, ASP)                                                         \
    {                                                                             \
        bf16x8 af_[8];                                                            \
        _Pragma("unroll")                                                         \
        for (int i_ = 0; i_ < 8; ++i_)                                            \
            af_[i_] = *(const bf16x8*)&(ASP)[(i_ * 16 + m16) * 32 + quad * 8];    \
        bf16x8 bfr_[2];                                                           \
        _Pragma("unroll")                                                         \
        for (int j_ = 0; j_ < 2; ++j_) {                                          \
            const int row_ = ((KK) << 7) | (ob + j_ * 16 + m16);                  \
            const int u_ = SU[row_];                                              \
            const float2 g_ = PG[row_];                                           \
            const uint32_t* Xr0_ = &(XP)[u_ * 16];                                \
            const uint32_t* Xr1_ = Xr0_ + 16;                                     \
            const int s0_ = u_ & 7, s1_ = (u_ + 1) & 7;                           \
            const uint2 a0_ = *(const uint2*)&Xr0_[((q2     ^ s0_) << 1)];        \
            const uint2 a1_ = *(const uint2*)&Xr0_[(((q2+1) ^ s0_) << 1)];        \
            const uint2 c0_ = *(const uint2*)&Xr1_[((q2     ^ s1_) << 1)];        \
            const uint2 c1_ = *(const uint2*)&Xr1_[(((q2+1) ^ s1_) << 1)];        \
            uint4 rr_;                                                            \
            rr_.x = interp1(a0_.x, c0_.x, g_.x, g_.y);                            \
            rr_.y = interp1(a0_.y, c0_.y, g_.x, g_.y);                            \
            rr_.z = interp1(a1_.x, c1_.x, g_.x, g_.y);                            \
            rr_.w = interp1(a1_.y, c1_.y, g_.x, g_.y);                            \
            __builtin_memcpy(&bfr_[j_], &rr_, 16);                                \
        }                                                                         \
        _Pragma("unroll")                                                         \
        for (int i_ = 0; i_ < 8; ++i_) {                                          \
            _Pragma("unroll")                                                     \
            for (int j_ = 0; j_ < 2; ++j_)                                        \
                acc[i_][j_] = __builtin_amdgcn_mfma_f32_16x16x32_bf16(af_[i_], bfr_[j_], acc[i_][j_], 0, 0, 0); \
        }                                                                         \
    }

#define HALF(CCB, A0_, A1_, A2_, A3_)                                             \
    ISSUE_A(2, (CCB), A2_); ISSUE_A(3, (CCB), A3_); ISSUE_XTB((CCB) + 1, XTB1);   \
    STEP(0, XTB0, A0_); STEP(1, XTB0, A1_); __syncthreads();                      \
    ISSUE_A(4, (CCB), A0_); ISSUE_A(5, (CCB), A1_);                               \
    STEP(2, XTB0, A2_); STEP(3, XTB0, A3_); __syncthreads();                      \
    ISSUE_A(6, (CCB), A2_); ISSUE_A(0, (CCB) + 1, A3_);                           \
    STEP(4, XTB0, A0_); STEP(5, XTB0, A1_); __syncthreads();                      \
    ISSUE_A(1, (CCB) + 1, A0_); ISSUE_A(2, (CCB) + 1, A1_);                       \
    STEP(6, XTB0, A2_); STEP(0, XTB1, A3_); __syncthreads();                      \
    ISSUE_A(3, (CCB) + 1, A2_); ISSUE_A(4, (CCB) + 1, A3_);                       \
    if ((CCB) + 2 < 16) { ISSUE_XTB((CCB) + 2, XTB0); }                           \
    STEP(1, XTB1, A0_); STEP(2, XTB1, A1_); __syncthreads();                      \
    ISSUE_A(5, (CCB) + 1, A0_); ISSUE_A(6, (CCB) + 1, A1_);                       \
    STEP(3, XTB1, A2_); STEP(4, XTB1, A3_); __syncthreads();                      \
    if ((CCB) + 2 < 16) { ISSUE_A(0, (CCB) + 2, A2_); ISSUE_A(1, (CCB) + 2, A3_); } \
    STEP(5, XTB1, A0_); STEP(6, XTB1, A1_); __syncthreads();

    f32x4 acc[8][2];
    #pragma unroll
    for (int i = 0; i < 8; ++i) {
        #pragma unroll
        for (int j = 0; j < 2; ++j) acc[i][j] = (f32x4){0.f, 0.f, 0.f, 0.f};
    }

    ISSUE_XTB(0, XTB0);
    ISSUE_A(0, 0, As0);
    ISSUE_A(1, 0, As1);
    for (int e = tid; e < 896; e += 256) {
        const int k  = e >> 7;
        const int ol = e & 127;
        int o = o0 + ol; if (o > OUT_LEN - 1) o = OUT_LEN - 1;
        const float t0  = (float)o;
        const float off = offs[((size_t)b * OUT_LEN + o) * K_ + k];
        float T = t0 + (float)k + off;
        T = fmaxf(T, t0);
        T = fminf(T, t0 + 6.0f);
        int u0 = (int)floorf(T);
        if (u0 > L_ - 2) u0 = L_ - 2;
        const float g0 = fmaxf(1.0f - fabsf((float)u0 - T), 0.0f);
        const float g1 = fmaxf(1.0f - fabsf((float)(u0 + 1) - T), 0.0f);
        SU[e] = u0 - o0;
        PG[e] = make_float2(g0, g1);
    }
    __syncthreads();

    #pragma unroll 1
    for (int s4 = 0; s4 < 16; s4 += 4) {
        HALF(s4,     As0, As1, As2, As3)
        HALF(s4 + 2, As2, As3, As0, As1)
    }

    #pragma unroll
    for (int i = 0; i < 8; ++i) {
        const int dd = d0 + i * 16 + quad * 4;
        float bv[4];
        #pragma unroll
        for (int r = 0; r < 4; ++r) bv[r] = bias[dd + r];
        #pragma unroll
        for (int j = 0; j < 2; ++j) {
            const int oo = o0 + ob + j * 16 + m16;
            if (oo < OUT_LEN) {
                float* op = out + (size_t)b * COUT * OUT_LEN + (size_t)dd * OUT_LEN + oo;
                #pragma unroll
                for (int r = 0; r < 4; ++r)
                    op[(size_t)r * OUT_LEN] = acc[i][j][r] + bv[r];
            }
        }
    }
#undef ISSUE_A
#undef ISSUE_XTB
#undef STEP
#undef HALF
}

// ---------------- fp32 fallback (round-1 kernel, used only if ws too small) ----------------
#define BM 64
#define BN 64
#define BC 8
#define TT (BC * K_)

__global__ __launch_bounds__(256, 2)
void deform_conv1d_fallback(const float* __restrict__ x, const float* __restrict__ offsets,
                            const float* __restrict__ weight, const float* __restrict__ bias,
                            float* __restrict__ out) {
    const int o0 = blockIdx.x * BN, d0 = blockIdx.y * BM, b = blockIdx.z, tid = threadIdx.x;
    __shared__ int   SU[BN * K_];
    __shared__ float SG0[BN * K_], SG1[BN * K_];
    __shared__ float XT[BC][BN + 8];
    __shared__ float S[BC][K_][BN];
    __shared__ float WT[BM][TT + 1];
    for (int e = tid; e < BN * K_; e += 256) {
        const int ol = e / K_, k = e % K_, o = o0 + ol;
        int u0rel = 0; float g0 = 0.f, g1 = 0.f;
        if (o < OUT_LEN) {
            const float t0 = (float)o;
            const float off = offsets[(size_t)b * OUT_LEN * K_ + (size_t)o * K_ + k];
            float T = fminf(fmaxf(t0 + (float)k + off, t0), t0 + 6.0f);
            int u0 = (int)floorf(T); if (u0 > L_ - 2) u0 = L_ - 2;
            g0 = fmaxf(1.0f - fabsf((float)u0 - T), 0.0f);
            g1 = fmaxf(1.0f - fabsf((float)(u0 + 1) - T), 0.0f);
            u0rel = u0 - o0;
        }
        SU[e] = u0rel; SG0[e] = g0; SG1[e] = g1;
    }
    float acc[4][4];
    #pragma unroll
    for (int i = 0; i < 4; ++i) {
        #pragma unroll
        for (int j = 0; j < 4; ++j) acc[i][j] = 0.f;
    }
    const int ty = tid >> 4, tx = tid & 15;
    const float* xb = x + (size_t)b * CIN * L_;
    for (int c0 = 0; c0 < CIN; c0 += BC) {
        __syncthreads();
        for (int e = tid; e < BC * (BN + 7); e += 256) {
            const int cl = e / (BN + 7), j = e % (BN + 7), pos = o0 + j;
            XT[cl][j] = (pos < L_) ? xb[(size_t)(c0 + cl) * L_ + pos] : 0.f;
        }
        for (int e = tid; e < BM * TT; e += 256) {
            const int d = e / TT, t = e % TT;
            WT[d][t] = weight[(size_t)(d0 + d) * (CIN * K_) + c0 * K_ + t];
        }
        __syncthreads();
        for (int e = tid; e < BC * K_ * BN; e += 256) {
            const int cl = e / (K_ * BN), r = e % (K_ * BN), k = r / BN, ol = r % BN;
            const int p = ol * K_ + k, u = SU[p];
            S[cl][k][ol] = SG0[p] * XT[cl][u] + SG1[p] * XT[cl][u + 1];
        }
        __syncthreads();
        #pragma unroll
        for (int t = 0; t < TT; ++t) {
            const int cl = t / K_, k = t % K_;
            const float4 s4 = *(const float4*)&S[cl][k][tx * 4];
            const float w0 = WT[ty * 4 + 0][t], w1 = WT[ty * 4 + 1][t];
            const float w2 = WT[ty * 4 + 2][t], w3 = WT[ty * 4 + 3][t];
            acc[0][0] += w0 * s4.x; acc[0][1] += w0 * s4.y; acc[0][2] += w0 * s4.z; acc[0][3] += w0 * s4.w;
            acc[1][0] += w1 * s4.x; acc[1][1] += w1 * s4.y; acc[1][2] += w1 * s4.z; acc[1][3] += w1 * s4.w;
            acc[2][0] += w2 * s4.x; acc[2][1] += w2 * s4.y; acc[2][2] += w2 * s4.z; acc[2][3] += w2 * s4.w;
            acc[3][0] += w3 * s4.x; acc[3][1] += w3 * s4.y; acc[3][2] += w3 * s4.z; acc[3][3] += w3 * s4.w;
        }
    }
    #pragma unroll
    for (int i = 0; i < 4; ++i) {
        const int d = d0 + ty * 4 + i;
        const float bvv = bias[d];
        #pragma unroll
        for (int j = 0; j < 4; ++j) {
            const int o = o0 + tx * 4 + j;
            if (o < OUT_LEN)
                out[(size_t)b * COUT * OUT_LEN + (size_t)d * OUT_LEN + o] = acc[i][j] + bvv;
        }
    }
}

extern "C" void kernel_launch(void* const* d_in, const int* in_sizes, int n_in,
                              void* d_out, int out_size, void* d_ws, size_t ws_size,
                              hipStream_t stream) {
    const float* x       = (const float*)d_in[0];
    const float* offsets = (const float*)d_in[1];
    const float* weight  = (const float*)d_in[2];
    const float* bias    = (const float*)d_in[3];
    float* out = (float*)d_out;

    const size_t WR_BYTES = (size_t)512 * 512 * 7 * 2;                  // 3,670,016
    const size_t P_BYTES  = (size_t)4 * 16 * 7 * 32 * 8192;             // 117,440,512
    const size_t XP_BYTES = (size_t)2048 * 544 * 16 + 512;              // 17,826,304

    if (ws_size >= WR_BYTES + P_BYTES) {
        // new path: precomputed interp + counted-vmcnt DMA-pipelined GEMM
        uint32_t* Wr_u32 = (uint32_t*)d_ws;
        ushort_t* Wr     = (ushort_t*)d_ws;
        uint32_t* P      = (uint32_t*)((char*)d_ws + WR_BYTES);
        reorder_w2_kernel<<<512, 256, 0, stream>>>(weight, Wr_u32);
        interp_pack_kernel<<<dim3(32, 16, B_), 256, 0, stream>>>(x, offsets, P);
        gemm_kernel<<<dim3(32, 4, B_), 256, 0, stream>>>(Wr, P, bias, out);
        return;
    }

    if (ws_size >= WR_BYTES + XP_BYTES) {
        // old verified path
        uint32_t* Wr_u32 = (uint32_t*)d_ws;
        ushort_t* Wr     = (ushort_t*)d_ws;
        uint32_t* xpack  = (uint32_t*)((char*)d_ws + WR_BYTES);
        reorder_w1_kernel<<<512, 256, 0, stream>>>(weight, Wr_u32);
        prepack_kernel<<<dim3(32, 16, B_), 256, 0, stream>>>(x, xpack);
        fused_v1_kernel<<<dim3(32, 4, B_), 256, 0, stream>>>(offsets, Wr, xpack, bias, out);
        return;
    }

    dim3 grid((OUT_LEN + BN - 1) / BN, COUT / BM, B_);
    deform_conv1d_fallback<<<grid, 256, 0, stream>>>(x, offsets, weight, bias, out);
}